// Round 21
// baseline (472.229 us; speedup 1.0000x reference)
//
#include <hip/hip_runtime.h>
#include <hip/hip_bf16.h>

constexpr int B_   = 4;
constexpr int CCH  = 256;   // feature channels
constexpr int CIN  = 128;   // Cch/2
constexpr int CINT = 16;    // Cch/16
constexpr int HH   = 128;
constexpr int WW   = 128;
constexpr int P_   = HH * WW;   // 16384
constexpr int HS   = 64;
constexpr int WS   = 64;

typedef __attribute__((ext_vector_type(8))) short bf16x8_t;
typedef __attribute__((ext_vector_type(4))) float f32x4_t;
typedef __attribute__((ext_vector_type(4))) unsigned short u16x4_t;

// keep original stub symbol
__global__ void CCCrossLayerAttentionV_76227079569757_kernel() {}

__device__ __forceinline__ unsigned short f32_to_bf16(float f) {
    unsigned u = __float_as_uint(f);
    u += 0x7fff + ((u >> 16) & 1);     // round-to-nearest-even (finite inputs)
    return (unsigned short)(u >> 16);
}

__device__ __forceinline__ float bf16_to_f32(unsigned short s) {
    unsigned u = ((unsigned)s) << 16;
    return __uint_as_float(u);
}

// ---------- fill d_out with a constant (diagnostics only) ----------
__global__ __launch_bounds__(256) void fill_f32_kernel(float* p, float v, unsigned long long n) {
    unsigned long long i = (unsigned long long)blockIdx.x * blockDim.x + threadIdx.x;
    unsigned long long stride = (unsigned long long)gridDim.x * blockDim.x;
    for (; i < n; i += stride) p[i] = v;
}

// ---------- convert Wc2 / Wv / Wb / Wk to bf16 (contiguous in one ws region) ----------
__global__ __launch_bounds__(256) void prep_w_kernel(const float* Wc2, const float* Wv,
                                                     const float* Wb, const float* Wk,
                                                     unsigned short* outw) {
    int idx = blockIdx.x * 256 + threadIdx.x;
    if (idx < 32768)        outw[idx] = f32_to_bf16(Wc2[idx]);
    else if (idx < 49152)   outw[idx] = f32_to_bf16(Wv[idx - 32768]);
    else if (idx < 147456)  outw[idx] = f32_to_bf16(Wb[idx - 49152]);
    else if (idx < 149504)  outw[idx] = f32_to_bf16(Wk[idx - 147456]);
}

// ---------- plane transpose f32: out[p][w][h] = in[p][h][w] ----------
__global__ __launch_bounds__(256) void transpose128_kernel(const float* __restrict__ in,
                                                           float* __restrict__ out) {
    __shared__ float tile[32][33];
    const int p = blockIdx.z;
    const int h0 = blockIdx.y * 32, w0 = blockIdx.x * 32;
    const float* ip = in + (size_t)p * P_;
    float* op = out + (size_t)p * P_;
    const int col = threadIdx.x & 31, r8 = threadIdx.x >> 5;
#pragma unroll
    for (int k = 0; k < 4; ++k) {
        int r = r8 + k * 8;
        tile[r][col] = ip[(h0 + r) * WW + w0 + col];
    }
    __syncthreads();
#pragma unroll
    for (int k = 0; k < 4; ++k) {
        int r = r8 + k * 8;
        op[(w0 + r) * HH + h0 + col] = tile[col][r];
    }
}

// ---------- plane transpose bf16 -> bf16 ----------
__global__ __launch_bounds__(256) void transpose128_b16_kernel(const unsigned short* __restrict__ in,
                                                               unsigned short* __restrict__ out) {
    __shared__ unsigned short tile[32][34];
    const int p = blockIdx.z;
    const int h0 = blockIdx.y * 32, w0 = blockIdx.x * 32;
    const unsigned short* ip = in + (size_t)p * P_;
    unsigned short* op = out + (size_t)p * P_;
    const int col = threadIdx.x & 31, r8 = threadIdx.x >> 5;
#pragma unroll
    for (int k = 0; k < 4; ++k) {
        int r = r8 + k * 8;
        tile[r][col] = ip[(h0 + r) * WW + w0 + col];
    }
    __syncthreads();
#pragma unroll
    for (int k = 0; k < 4; ++k) {
        int r = r8 + k * 8;
        op[(w0 + r) * HH + h0 + col] = tile[col][r];
    }
}

// ---------- fused merge (bf16 carrier): vB[c][h][w] += outW[c][h][w] + outHT[c][w][h] ----------
__global__ __launch_bounds__(256) void merge_hw_kernel(const unsigned short* __restrict__ outHT,
                                                       const unsigned short* __restrict__ outW,
                                                       unsigned short* __restrict__ vB) {
    __shared__ float tile[32][33];
    const int plane = blockIdx.z;
    const int w0 = blockIdx.x * 32, h0 = blockIdx.y * 32;
    const unsigned short* ip = outHT + (size_t)plane * P_;
    const int col = threadIdx.x & 31, r8 = threadIdx.x >> 5;
#pragma unroll
    for (int k = 0; k < 4; ++k) {
        int r = r8 + k * 8;          // r indexes w
        tile[r][col] = bf16_to_f32(ip[(w0 + r) * HH + h0 + col]);
    }
    __syncthreads();
#pragma unroll
    for (int k = 0; k < 4; ++k) {
        int r = r8 + k * 8;          // r indexes h
        size_t o = (size_t)plane * P_ + (h0 + r) * WW + w0 + col;
        float v = bf16_to_f32(vB[o]) + tile[col][r] + bf16_to_f32(outW[o]);
        vB[o] = f32_to_bf16(v);
    }
}

// ---------- upsample + transpose: high f32 [b][c][64][64] -> highT bf16 [b][p][CCH] ----------
__global__ __launch_bounds__(256) void upsampleT_kernel(const float* __restrict__ high,
                                                        unsigned short* __restrict__ highT) {
    const int h = blockIdx.x, c0 = blockIdx.y * 64, b = blockIdx.z;
    const int tid = threadIdx.x;
    __shared__ float r0[64][65], r1[64][65];
    float fy = 0.5f * h - 0.25f;
    int y0 = (int)floorf(fy);
    float wy = fy - (float)y0;
    int y0c = y0 < 0 ? 0 : y0;
    int y1c = (y0 + 1 > HS - 1) ? (HS - 1) : (y0 + 1);
#pragma unroll
    for (int e = 0; e < 16; ++e) {
        int flat = tid + e * 256;       // 4096 tasks: (c, x)
        int c = flat >> 6, x = flat & 63;
        const float* pl = high + (size_t)(b * CCH + c0 + c) * (HS * WS);
        r0[c][x] = pl[y0c * WS + x];
        r1[c][x] = pl[y1c * WS + x];
    }
    __syncthreads();
#pragma unroll
    for (int e = 0; e < 8; ++e) {
        int flat = tid + e * 256;       // 2048 tasks: (w, c-quad) — 64 ch per block
        int w = flat >> 4, q = flat & 15;
        float fx = 0.5f * w - 0.25f;
        int x0 = (int)floorf(fx);
        float wx = fx - (float)x0;
        int x0c = x0 < 0 ? 0 : x0;
        int x1c = (x0 + 1 > WS - 1) ? (WS - 1) : (x0 + 1);
        u16x4_t o;
#pragma unroll
        for (int k = 0; k < 4; ++k) {
            int c = 4 * q + k;
            float v0 = r0[c][x0c] + wx * (r0[c][x1c] - r0[c][x0c]);
            float v1 = r1[c][x0c] + wx * (r1[c][x1c] - r1[c][x0c]);
            o[k] = f32_to_bf16(v0 + wy * (v1 - v0));
        }
        *(u16x4_t*)&highT[((size_t)(b * P_) + h * WW + w) * CCH + c0 + 4 * q] = o;
    }
}

// ---------- transpose-cast: low f32 [b][CCH][h][w] -> lowT bf16 [b][p][CCH] ----------
__global__ __launch_bounds__(256) void lowT_kernel(const float* __restrict__ low,
                                                   unsigned short* __restrict__ lowT) {
    const int h = blockIdx.x, ch0 = blockIdx.y * 128, b = blockIdx.z;
    const int tid = threadIdx.x;
    __shared__ unsigned short st[128][136];
#pragma unroll
    for (int e = 0; e < 16; ++e) {
        int flat = tid + e * 256;       // 4096 float4 tasks: (c, w-quad)
        int c = flat >> 5, wq = flat & 31;
        float4 u = *(const float4*)(low + (size_t)(b * CCH + ch0 + c) * P_ + h * WW + 4 * wq);
        u16x4_t o;
        o[0] = f32_to_bf16(u.x); o[1] = f32_to_bf16(u.y);
        o[2] = f32_to_bf16(u.z); o[3] = f32_to_bf16(u.w);
        *(u16x4_t*)&st[c][4 * wq] = o;
    }
    __syncthreads();
#pragma unroll
    for (int e = 0; e < 16; ++e) {
        int flat = tid + e * 256;       // 4096 tasks = 128 w x 32 c-quads
        int w = flat >> 5, q = flat & 31;
        u16x4_t o;
#pragma unroll
        for (int k = 0; k < 4; ++k) o[k] = st[4 * q + k][w];
        *(u16x4_t*)&lowT[((size_t)(b * P_) + h * WW + w) * CCH + ch0 + 4 * q] = o;
    }
}

// ---------- transpose: vB bf16 [b][CIN][h][w] -> valT bf16 [b][p][CIN] ----------
__global__ __launch_bounds__(256) void tcast_kernel(const unsigned short* __restrict__ vB,
                                                    unsigned short* __restrict__ valT) {
    const int h = blockIdx.x, b = blockIdx.y;
    const int tid = threadIdx.x;
    __shared__ unsigned short st[CIN][136];
#pragma unroll
    for (int e = 0; e < 8; ++e) {
        int idx = tid + e * 256;        // 2048 bf16x8 tasks: (c, w-oct)
        int c = idx >> 4, oct = idx & 15;
        *(bf16x8_t*)&st[c][oct * 8] =
            *(const bf16x8_t*)&vB[(size_t)(b * CIN + c) * P_ + h * WW + oct * 8];
    }
    __syncthreads();
#pragma unroll
    for (int e = 0; e < 16; ++e) {
        int flat = tid + e * 256;       // 4096 tasks = 128 w x 32 c-quads
        int w = flat >> 5, q = flat & 31;
        u16x4_t o;
#pragma unroll
        for (int k = 0; k < 4; ++k) o[k] = st[4 * q + k][w];
        *(u16x4_t*)&valT[((size_t)(b * P_) + h * WW + w) * CIN + 4 * q] = o;
    }
}

// ---------- fold Wpq = Wq @ Wc1 (16x512) f32 + bf16; bpq = Wq @ bc1 + bq ----------
__global__ __launch_bounds__(256) void fold_wq_kernel(const float* __restrict__ Wq,
                                                      const float* __restrict__ bq,
                                                      const float* __restrict__ Wc1,
                                                      const float* __restrict__ bc1,
                                                      float* __restrict__ Wpq,
                                                      unsigned short* __restrict__ Wpq16,
                                                      float* __restrict__ bpq) {
    int idx = blockIdx.x * 256 + threadIdx.x;
    if (idx < CINT * 2 * CCH) {
        int o = idx / (2 * CCH), i = idx % (2 * CCH);
        float acc = 0.f;
#pragma unroll 8
        for (int m = 0; m < CIN; ++m)
            acc = fmaf(Wq[o * CIN + m], Wc1[m * (2 * CCH) + i], acc);
        Wpq[idx] = acc;
        Wpq16[idx] = f32_to_bf16(acc);
    }
    if (blockIdx.x == 0 && threadIdx.x < CINT) {
        int t = threadIdx.x;
        float acc = bq[t];
        for (int m = 0; m < CIN; ++m) acc = fmaf(Wq[t * CIN + m], bc1[m], acc);
        bpq[t] = acc;
    }
}

// ---------- tiny-M global-direct MFMA conv: D[o<16][p] = sum_k W[o][k]*XT[p][k] + bias ----------
template <int K1, int K2>
__global__ __launch_bounds__(256) void mfma_conv16_kernel(
    const unsigned short* __restrict__ XT1, const unsigned short* __restrict__ XT2,
    const unsigned short* __restrict__ W16, const float* __restrict__ bias,
    float* __restrict__ outF) {
    constexpr int K = K1 + K2;
    const int tid = threadIdx.x, lane = tid & 63, wave = tid >> 6;
    const int p0 = blockIdx.x * 64, b = blockIdx.z;
    const int fl = lane & 15, koff = (lane >> 4) * 8;
    const int pw = p0 + wave * 16 + fl;   // this lane's pixel for B-frags

    const unsigned short* X1b = XT1 + ((size_t)b * P_ + pw) * K1;
    const unsigned short* X2b = (K2 > 0) ? XT2 + ((size_t)b * P_ + pw) * K2
                                         : (const unsigned short*)nullptr;
    f32x4_t acc = (f32x4_t)0.f;
#pragma unroll
    for (int k0 = 0; k0 < K; k0 += 32) {
        bf16x8_t a = *(const bf16x8_t*)&W16[fl * K + k0 + koff];
        bf16x8_t bf;
        if (K2 == 0 || k0 < K1) bf = *(const bf16x8_t*)&X1b[k0 + koff];
        else                    bf = *(const bf16x8_t*)&X2b[(k0 - K1) + koff];
        acc = __builtin_amdgcn_mfma_f32_16x16x32_bf16(a, bf, acc, 0, 0, 0);
    }
#pragma unroll
    for (int j = 0; j < 4; ++j) {
        int o = (lane >> 4) * 4 + j;
        outF[((size_t)(b * CINT + o)) * P_ + p0 + wave * 16 + fl] = acc[j] + bias[o];
    }
}

// ---------- global-direct MFMA conv (128-px tiles): D[c][p] = sum_k W[c][k]*XT[p][k] ----------
// MODE 1: relu(BN) f32 [c][p]. MODE 3: +bias bf16 [c][p]. MODE 4: MODE 3 + bf16 [p][c] (outT).
// R21: K-loop unroll 2 -> 4 (deeper load pipelining; single-knob ILP experiment)
template <int K1, int K2, int MODE>
__global__ __launch_bounds__(256) void mfma_convT_kernel(
    const unsigned short* __restrict__ XT1, const unsigned short* __restrict__ XT2,
    const unsigned short* __restrict__ W16, const float* __restrict__ bias,
    float* __restrict__ outF, unsigned short* __restrict__ outT,
    unsigned short* __restrict__ outCP, int Cout,
    const float* __restrict__ bn_g, const float* __restrict__ bn_b,
    const float* __restrict__ bn_m, const float* __restrict__ bn_v) {
    constexpr int K = K1 + K2;
    const int tid = threadIdx.x, lane = tid & 63, wave = tid >> 6;
    const int p0 = blockIdx.x * 128, oBase = blockIdx.y * 128, b = blockIdx.z;
    const int fl = lane & 15, koff = (lane >> 4) * 8;

    const unsigned short* X1b = XT1 + ((size_t)b * P_ + p0 + wave * 32) * K1;
    const unsigned short* X2b = (K2 > 0) ? XT2 + ((size_t)b * P_ + p0 + wave * 32) * K2
                                         : (const unsigned short*)nullptr;
    const unsigned short* Wb0 = W16 + (size_t)oBase * K;

    f32x4_t acc[8][2];
#pragma unroll
    for (int ci = 0; ci < 8; ++ci) {
        acc[ci][0] = (f32x4_t)0.f;
        acc[ci][1] = (f32x4_t)0.f;
    }

#pragma unroll 4
    for (int k0 = 0; k0 < K; k0 += 32) {
        bf16x8_t bfr[2];
#pragma unroll
        for (int ni = 0; ni < 2; ++ni) {
            int pr = ni * 16 + fl;
            if (K2 == 0 || k0 < K1)
                bfr[ni] = *(const bf16x8_t*)&X1b[(size_t)pr * K1 + k0 + koff];
            else
                bfr[ni] = *(const bf16x8_t*)&X2b[(size_t)pr * K2 + (k0 - K1) + koff];
        }
        bf16x8_t afr[8];
#pragma unroll
        for (int ci = 0; ci < 8; ++ci)
            afr[ci] = *(const bf16x8_t*)&Wb0[(size_t)(ci * 16 + fl) * K + k0 + koff];
#pragma unroll
        for (int ci = 0; ci < 8; ++ci) {
            acc[ci][0] = __builtin_amdgcn_mfma_f32_16x16x32_bf16(afr[ci], bfr[0], acc[ci][0], 0, 0, 0);
            acc[ci][1] = __builtin_amdgcn_mfma_f32_16x16x32_bf16(afr[ci], bfr[1], acc[ci][1], 0, 0, 0);
        }
    }

    const int csub = (lane >> 4) * 4;
#pragma unroll
    for (int ci = 0; ci < 8; ++ci) {
        int cb = oBase + ci * 16 + csub;
#pragma unroll
        for (int ni = 0; ni < 2; ++ni) {
            int p = p0 + wave * 32 + ni * 16 + fl;
            u16x4_t t;
#pragma unroll
            for (int j = 0; j < 4; ++j) {
                float v = acc[ci][ni][j];
                int o = cb + j;
                if (MODE == 1) {
                    float sc = rsqrtf(bn_v[o] + 1e-5f) * bn_g[o];
                    v = fmaxf((v - bn_m[o]) * sc + bn_b[o], 0.f);
                } else {
                    v += bias ? bias[o] : 0.f;
                }
                if (MODE == 3 || MODE == 4) {
                    unsigned short bv = f32_to_bf16(v);
                    outCP[((size_t)(b * Cout + o)) * P_ + p] = bv;
                    if (MODE == 4) t[j] = bv;
                } else {
                    outF[((size_t)(b * Cout + o)) * P_ + p] = v;
                }
            }
            if (MODE == 4)
                *(u16x4_t*)&outT[((size_t)(b * P_) + p) * Cout + cb] = t;
        }
    }
}

// ---------- fused scores + softmax + attH write + MFMA PV-W -> outW (bf16) ----------
__global__ __launch_bounds__(256) void attn_fused_w_kernel(
    const float* __restrict__ pq, const float* __restrict__ pk,
    const float* __restrict__ pkT, const unsigned short* __restrict__ pvB,
    const float* __restrict__ gamma_p, unsigned short* __restrict__ outW,
    unsigned short* __restrict__ attH) {
    const int w0 = blockIdx.x * 32;
    const int h  = blockIdx.y;
    const int b  = blockIdx.z;
    const int tid = threadIdx.x;

    __shared__ float s_s[32][257];
    __shared__ float pq_s[CINT][32];
    __shared__ _Float16 pkW_s[CINT][128];
    __shared__ float rr[32][8];
    __shared__ float rowinv[32];
    __shared__ __align__(16) unsigned short attW_s[32][136];

    for (int e = tid; e < CINT * 32; e += 256) {
        int c = e >> 5, wl = e & 31;
        pq_s[c][wl] = pq[(unsigned)((b * CINT + c) * P_ + h * WW + w0 + wl)];
    }
    for (int e = tid; e < CINT * 128; e += 256) {
        int c = e >> 7, x = e & 127;
        pkW_s[c][x] = (_Float16)pk[(unsigned)((b * CINT + c) * P_ + h * WW + x)];
    }
    __syncthreads();

    const int x = tid;
    if (x < HH) {
        const float* base = pkT + (unsigned)(b * CINT * P_ + w0 * HH + x);
#pragma unroll 2
        for (int wl = 0; wl < 32; ++wl) {
            const float* pp = base + wl * HH;
            float dot = 0.f;
#pragma unroll
            for (int c = 0; c < CINT; ++c)
                dot = fmaf(pq_s[c][wl], pp[c * P_], dot);
            if (x == h) dot = -1e9f;
            s_s[wl][x] = dot;
        }
    } else {
        const int xx = x - HH;
#pragma unroll 4
        for (int wl = 0; wl < 32; ++wl) {
            float dot = 0.f;
#pragma unroll
            for (int c = 0; c < CINT; ++c)
                dot = fmaf(pq_s[c][wl], (float)pkW_s[c][xx], dot);
            s_s[wl][x] = dot;
        }
    }
    __syncthreads();

    const int row = tid >> 3, sub = tid & 7;
    float pm = -3.4e38f;
    for (int xx = sub; xx < 256; xx += 8) pm = fmaxf(pm, s_s[row][xx]);
    rr[row][sub] = pm;
    __syncthreads();
    float m = rr[row][0];
    for (int k = 1; k < 8; ++k) m = fmaxf(m, rr[row][k]);
    float ps = 0.f;
    for (int xx = sub; xx < 256; xx += 8) {
        float ex = __expf(s_s[row][xx] - m);
        s_s[row][xx] = ex;
        ps += ex;
    }
    __syncthreads();
    rr[row][sub] = ps;
    __syncthreads();
    if (sub == 0) {
        float s = 0.f;
        for (int k = 0; k < 8; ++k) s += rr[row][k];
        rowinv[row] = 1.f / s;
    }
    __syncthreads();

#pragma unroll
    for (int e = 0; e < 16; ++e) {
        int idx = tid + e * 256;
        int wl = idx >> 7, xx = idx & 127;
        attH[(((size_t)b * WW + (w0 + wl)) * HH + h) * 128 + xx] =
            f32_to_bf16(s_s[wl][xx] * rowinv[wl]);
    }
#pragma unroll
    for (int e = 0; e < 16; ++e) {
        int idx = tid + e * 256;
        int wl = idx >> 7, xx = idx & 127;
        attW_s[wl][xx] = f32_to_bf16(s_s[wl][128 + xx] * rowinv[wl]);
    }
    __syncthreads();

    // MFMA PV-W: D[c][w] = sum_x pvB[c,h,x] * attW[w,x]  (pvB bf16, direct b128 A-frags)
    const int lane = tid & 63, wave = tid >> 6;
    const int fl = lane & 15, koff = (lane >> 4) * 8;
    const int c0 = wave * 32;
    f32x4_t acc[2][2];
#pragma unroll
    for (int mi = 0; mi < 2; ++mi)
#pragma unroll
        for (int nw = 0; nw < 2; ++nw) acc[mi][nw] = (f32x4_t)0.f;

    const unsigned short* pvBase = pvB + (size_t)b * CIN * P_ + (size_t)h * WW;
#pragma unroll
    for (int ks = 0; ks < 4; ++ks) {
        int x0 = ks * 32 + koff;
        bf16x8_t a0 = *(const bf16x8_t*)&pvBase[(size_t)(c0 + fl) * P_ + x0];
        bf16x8_t a1 = *(const bf16x8_t*)&pvBase[(size_t)(c0 + 16 + fl) * P_ + x0];
        bf16x8_t b0 = *(const bf16x8_t*)&attW_s[fl][x0];
        bf16x8_t b1 = *(const bf16x8_t*)&attW_s[16 + fl][x0];
        acc[0][0] = __builtin_amdgcn_mfma_f32_16x16x32_bf16(a0, b0, acc[0][0], 0, 0, 0);
        acc[0][1] = __builtin_amdgcn_mfma_f32_16x16x32_bf16(a0, b1, acc[0][1], 0, 0, 0);
        acc[1][0] = __builtin_amdgcn_mfma_f32_16x16x32_bf16(a1, b0, acc[1][0], 0, 0, 0);
        acc[1][1] = __builtin_amdgcn_mfma_f32_16x16x32_bf16(a1, b1, acc[1][1], 0, 0, 0);
    }

    const float g = gamma_p[0];
#pragma unroll
    for (int mi = 0; mi < 2; ++mi)
#pragma unroll
        for (int nw = 0; nw < 2; ++nw)
#pragma unroll
            for (int j = 0; j < 4; ++j) {
                int c = c0 + mi * 16 + (lane >> 4) * 4 + j;
                int w = w0 + nw * 16 + fl;
                outW[((size_t)b * CIN + c) * P_ + (size_t)h * WW + w] =
                    f32_to_bf16(g * acc[mi][nw][j]);
            }
}

// ---------- PV-H batched GEMM -> outHT[b][c][w][h] = g * sum_x pvT[c,w,x]*attH[h,x] ----------
__global__ __launch_bounds__(256) void pv_h_gemm_out_kernel(
    const unsigned short* __restrict__ pvT, const unsigned short* __restrict__ attH,
    const float* __restrict__ gamma_p, unsigned short* __restrict__ outHT) {
    const int ch = blockIdx.x, w = blockIdx.y, b = blockIdx.z;
    const int tid = threadIdx.x, lane = tid & 63, wave = tid >> 6;

    __shared__ __align__(16) unsigned short pvs[64][136];
    __shared__ __align__(16) unsigned short ahs[128][136];

    const unsigned short* pvTb = pvT + ((size_t)(b * CIN + ch * 64)) * P_ + (size_t)w * HH;
#pragma unroll
    for (int e = 0; e < 4; ++e) {
        int idx = tid + e * 256;
        int c = idx >> 4, oct = idx & 15;
        *(bf16x8_t*)&pvs[c][oct * 8] = *(const bf16x8_t*)&pvTb[(size_t)c * P_ + oct * 8];
    }
    const unsigned short* ah = attH + ((size_t)b * WW + w) * (HH * 128);
#pragma unroll
    for (int e = 0; e < 8; ++e) {
        int idx = tid + e * 256;
        int hh = idx >> 4, x0 = (idx & 15) * 8;
        *(bf16x8_t*)&ahs[hh][x0] = *(const bf16x8_t*)&ah[(size_t)idx * 8];
    }
    __syncthreads();

    const int fl = lane & 15, koff = (lane >> 4) * 8;
    f32x4_t acc[4][2];
#pragma unroll
    for (int mi = 0; mi < 4; ++mi)
#pragma unroll
        for (int nw = 0; nw < 2; ++nw) acc[mi][nw] = (f32x4_t)0.f;

#pragma unroll
    for (int ks = 0; ks < 4; ++ks) {
        int x0 = ks * 32 + koff;
        bf16x8_t b0 = *(const bf16x8_t*)&ahs[wave * 32 + fl][x0];
        bf16x8_t b1 = *(const bf16x8_t*)&ahs[wave * 32 + 16 + fl][x0];
#pragma unroll
        for (int mi = 0; mi < 4; ++mi) {
            bf16x8_t a = *(const bf16x8_t*)&pvs[mi * 16 + fl][x0];
            acc[mi][0] = __builtin_amdgcn_mfma_f32_16x16x32_bf16(a, b0, acc[mi][0], 0, 0, 0);
            acc[mi][1] = __builtin_amdgcn_mfma_f32_16x16x32_bf16(a, b1, acc[mi][1], 0, 0, 0);
        }
    }

    const float g = gamma_p[0];
    const int csub = (lane >> 4) * 4;
#pragma unroll
    for (int mi = 0; mi < 4; ++mi)
#pragma unroll
        for (int nw = 0; nw < 2; ++nw)
#pragma unroll
            for (int j = 0; j < 4; ++j) {
                int c = ch * 64 + mi * 16 + csub + j;
                int hh = wave * 32 + nw * 16 + fl;
                outHT[((size_t)(b * CIN + c) * WW + w) * HH + hh] =
                    f32_to_bf16(g * acc[mi][nw][j]);
            }
}

extern "C" void kernel_launch(void* const* d_in, const int* in_sizes, int n_in,
                              void* d_out, int out_size, void* d_ws, size_t ws_size,
                              hipStream_t stream) {
    const float* low   = (const float*)d_in[0];
    const float* high  = (const float*)d_in[1];
    const float* Wc1   = (const float*)d_in[2];
    const float* bc1   = (const float*)d_in[3];
    const float* Wc2   = (const float*)d_in[4];
    const float* bc2   = (const float*)d_in[5];
    const float* Wq    = (const float*)d_in[6];
    const float* bq    = (const float*)d_in[7];
    const float* Wk    = (const float*)d_in[8];
    const float* bk    = (const float*)d_in[9];
    const float* Wv    = (const float*)d_in[10];
    const float* bv    = (const float*)d_in[11];
    const float* gamma = (const float*)d_in[12];
    const float* Wb    = (const float*)d_in[13];
    const float* bng   = (const float*)d_in[14];
    const float* bnb   = (const float*)d_in[15];
    const float* bnm   = (const float*)d_in[16];
    const float* bnv   = (const float*)d_in[17];
    float* out = (float*)d_out;   // output is float32

    const unsigned long long outN = (unsigned long long)B_ * CCH * P_;

    // ---- ws layout (f32-eq elems) ----
    const size_t wpqOffA   = 0;
    const size_t bpqOffA   = 8192;
    const size_t wpq16OffA = 8208;
    const size_t wbfOffA   = wpq16OffA + 4096;
    const size_t pqOffA    = wbfOffA + 74784;
    const size_t pkOffA    = pqOffA + (size_t)B_ * CINT * P_;
    const size_t pkTOffA   = pkOffA + (size_t)B_ * CINT * P_;
    const size_t hTOffA    = pkTOffA + (size_t)B_ * CINT * P_;
    const size_t vtAOffA   = hTOffA + ((size_t)B_ * P_ * CCH) / 2;
    const size_t pvTOffA   = vtAOffA + ((size_t)B_ * P_ * CIN) / 2;
    const size_t needA = (pvTOffA + ((size_t)B_ * P_ * CIN) / 2) * sizeof(float);

    if (ws_size < needA) {
        fill_f32_kernel<<<dim3(2048), dim3(256), 0, stream>>>(out, 2.0f, outN);
        return;
    }

    float* Wpq = (float*)d_ws + wpqOffA;
    float* bpq = (float*)d_ws + bpqOffA;
    unsigned short* Wpq16 = (unsigned short*)((float*)d_ws + wpq16OffA);
    unsigned short* Wc2b = (unsigned short*)((float*)d_ws + wbfOffA);
    unsigned short* Wvb  = Wc2b + 32768;
    unsigned short* Wbb  = Wvb + 16384;
    unsigned short* Wkb  = Wbb + 98304;
    float* pqv  = (float*)d_ws + pqOffA;
    float* pkv  = (float*)d_ws + pkOffA;
    float* pkT  = (float*)d_ws + pkTOffA;
    unsigned short* highT = (unsigned short*)((float*)d_ws + hTOffA);
    unsigned short* vtA   = (unsigned short*)((float*)d_ws + vtAOffA);
    unsigned short* pvTb  = (unsigned short*)((float*)d_ws + pvTOffA);

    // d_out scratch: vB bf16 [c][p] (first half). Second half slots:
    //   lowT bf16 (dead after pq conv); per-iter: slot1 = pvB then outHT, slot2 = outW.
    unsigned short* vB = (unsigned short*)out;
    float* half2 = out + (size_t)B_ * CIN * P_;
    unsigned short* lowT  = (unsigned short*)half2;
    unsigned short* slot1 = (unsigned short*)half2;
    unsigned short* slot2 = (unsigned short*)half2 + (size_t)B_ * CIN * P_;

    prep_w_kernel<<<dim3(584), dim3(256), 0, stream>>>(Wc2, Wv, Wb, Wk, Wc2b);
    fold_wq_kernel<<<dim3(32), dim3(256), 0, stream>>>(Wq, bq, Wc1, bc1, Wpq, Wpq16, bpq);
    upsampleT_kernel<<<dim3(HH, CCH / 64, B_), dim3(256), 0, stream>>>(high, highT);
    lowT_kernel<<<dim3(HH, 2, B_), dim3(256), 0, stream>>>(low, lowT);

    // value = Wc2 @ up(high) + bc2  (MODE 4: bf16 vB [c][p] + bf16 vtA [p][c])
    mfma_convT_kernel<256, 0, 4><<<dim3(128, 1, B_), dim3(256), 0, stream>>>(
        highT, (const unsigned short*)0, Wc2b, bc2, (float*)0, vtA, vB, CIN,
        (const float*)0, (const float*)0, (const float*)0, (const float*)0);
    // pq = Wpq @ concat(up(high), low) + bpq  (tiny-M MFMA, K=512)
    mfma_conv16_kernel<256, 256><<<dim3(P_ / 64, 1, B_), dim3(256), 0, stream>>>(
        highT, lowT, Wpq16, bpq, pqv);

    for (int it = 0; it < 2; ++it) {
        // pk = Wk @ value + bk  (tiny-M MFMA, K=128)
        mfma_conv16_kernel<128, 0><<<dim3(P_ / 64, 1, B_), dim3(256), 0, stream>>>(
            vtA, (const unsigned short*)0, Wkb, bk, pkv);
        transpose128_kernel<<<dim3(4, 4, B_ * CINT), dim3(256), 0, stream>>>(pkv, pkT);
        // pv = Wv @ value + bv  (MODE 3: bf16 [c][p] into slot1; lowT dead now)
        mfma_convT_kernel<128, 0, 3><<<dim3(128, 1, B_), dim3(256), 0, stream>>>(
            vtA, (const unsigned short*)0, Wvb, bv, (float*)0, (unsigned short*)0, slot1, CIN,
            (const float*)0, (const float*)0, (const float*)0, (const float*)0);
        transpose128_b16_kernel<<<dim3(4, 4, B_ * CIN), dim3(256), 0, stream>>>(slot1, pvTb);
        // attn: W-direction PV -> outW (slot2); attH -> vtA. Reads pvB (slot1).
        attn_fused_w_kernel<<<dim3(WW / 32, HH, B_), dim3(256), 0, stream>>>(
            pqv, pkv, pkT, slot1, gamma, slot2, vtA);
        // H-direction PV -> outHT (slot1; pvB dead after attn)
        pv_h_gemm_out_kernel<<<dim3(2, WW, B_), dim3(256), 0, stream>>>(
            pvTb, vtA, gamma, slot1);
        // vB += outW + outHT^T  (single fused bf16 RMW pass)
        merge_hw_kernel<<<dim3(4, 4, B_ * CIN), dim3(256), 0, stream>>>(slot1, slot2, vB);
        // refresh valueT (overwrites attH in vtA)
        tcast_kernel<<<dim3(HH, B_), dim3(256), 0, stream>>>(vB, vtA);
    }
    // out = relu(BN(Wb @ concat(value, up(high))))  (MODE 1, 128-px tiles) — overwrites d_out
    mfma_convT_kernel<128, 256, 1><<<dim3(128, 2, B_), dim3(256), 0, stream>>>(
        vtA, highT, Wbb, (const float*)0, out, (unsigned short*)0, (unsigned short*)0, CCH,
        bng, bnb, bnm, bnv);
}

// Round 22
// 464.166 us; speedup vs baseline: 1.0174x; 1.0174x over previous
//
#include <hip/hip_runtime.h>
#include <hip/hip_bf16.h>

constexpr int B_   = 4;
constexpr int CCH  = 256;   // feature channels
constexpr int CIN  = 128;   // Cch/2
constexpr int CINT = 16;    // Cch/16
constexpr int HH   = 128;
constexpr int WW   = 128;
constexpr int P_   = HH * WW;   // 16384
constexpr int HS   = 64;
constexpr int WS   = 64;

typedef __attribute__((ext_vector_type(8))) short bf16x8_t;
typedef __attribute__((ext_vector_type(4))) float f32x4_t;
typedef __attribute__((ext_vector_type(4))) unsigned short u16x4_t;

// keep original stub symbol
__global__ void CCCrossLayerAttentionV_76227079569757_kernel() {}

__device__ __forceinline__ unsigned short f32_to_bf16(float f) {
    unsigned u = __float_as_uint(f);
    u += 0x7fff + ((u >> 16) & 1);     // round-to-nearest-even (finite inputs)
    return (unsigned short)(u >> 16);
}

__device__ __forceinline__ float bf16_to_f32(unsigned short s) {
    unsigned u = ((unsigned)s) << 16;
    return __uint_as_float(u);
}

// ---------- fill d_out with a constant (diagnostics only) ----------
__global__ __launch_bounds__(256) void fill_f32_kernel(float* p, float v, unsigned long long n) {
    unsigned long long i = (unsigned long long)blockIdx.x * blockDim.x + threadIdx.x;
    unsigned long long stride = (unsigned long long)gridDim.x * blockDim.x;
    for (; i < n; i += stride) p[i] = v;
}

// ---------- convert Wc2 / Wv / Wb / Wk to bf16 (contiguous in one ws region) ----------
__global__ __launch_bounds__(256) void prep_w_kernel(const float* Wc2, const float* Wv,
                                                     const float* Wb, const float* Wk,
                                                     unsigned short* outw) {
    int idx = blockIdx.x * 256 + threadIdx.x;
    if (idx < 32768)        outw[idx] = f32_to_bf16(Wc2[idx]);
    else if (idx < 49152)   outw[idx] = f32_to_bf16(Wv[idx - 32768]);
    else if (idx < 147456)  outw[idx] = f32_to_bf16(Wb[idx - 49152]);
    else if (idx < 149504)  outw[idx] = f32_to_bf16(Wk[idx - 147456]);
}

// ---------- plane transpose f32: out[p][w][h] = in[p][h][w] ----------
__global__ __launch_bounds__(256) void transpose128_kernel(const float* __restrict__ in,
                                                           float* __restrict__ out) {
    __shared__ float tile[32][33];
    const int p = blockIdx.z;
    const int h0 = blockIdx.y * 32, w0 = blockIdx.x * 32;
    const float* ip = in + (size_t)p * P_;
    float* op = out + (size_t)p * P_;
    const int col = threadIdx.x & 31, r8 = threadIdx.x >> 5;
#pragma unroll
    for (int k = 0; k < 4; ++k) {
        int r = r8 + k * 8;
        tile[r][col] = ip[(h0 + r) * WW + w0 + col];
    }
    __syncthreads();
#pragma unroll
    for (int k = 0; k < 4; ++k) {
        int r = r8 + k * 8;
        op[(w0 + r) * HH + h0 + col] = tile[col][r];
    }
}

// ---------- plane transpose bf16 -> bf16 ----------
__global__ __launch_bounds__(256) void transpose128_b16_kernel(const unsigned short* __restrict__ in,
                                                               unsigned short* __restrict__ out) {
    __shared__ unsigned short tile[32][34];
    const int p = blockIdx.z;
    const int h0 = blockIdx.y * 32, w0 = blockIdx.x * 32;
    const unsigned short* ip = in + (size_t)p * P_;
    unsigned short* op = out + (size_t)p * P_;
    const int col = threadIdx.x & 31, r8 = threadIdx.x >> 5;
#pragma unroll
    for (int k = 0; k < 4; ++k) {
        int r = r8 + k * 8;
        tile[r][col] = ip[(h0 + r) * WW + w0 + col];
    }
    __syncthreads();
#pragma unroll
    for (int k = 0; k < 4; ++k) {
        int r = r8 + k * 8;
        op[(w0 + r) * HH + h0 + col] = tile[col][r];
    }
}

// ---------- fused merge (bf16 carrier): vB[c][h][w] += outW[c][h][w] + outHT[c][w][h] ----------
__global__ __launch_bounds__(256) void merge_hw_kernel(const unsigned short* __restrict__ outHT,
                                                       const unsigned short* __restrict__ outW,
                                                       unsigned short* __restrict__ vB) {
    __shared__ float tile[32][33];
    const int plane = blockIdx.z;
    const int w0 = blockIdx.x * 32, h0 = blockIdx.y * 32;
    const unsigned short* ip = outHT + (size_t)plane * P_;
    const int col = threadIdx.x & 31, r8 = threadIdx.x >> 5;
#pragma unroll
    for (int k = 0; k < 4; ++k) {
        int r = r8 + k * 8;          // r indexes w
        tile[r][col] = bf16_to_f32(ip[(w0 + r) * HH + h0 + col]);
    }
    __syncthreads();
#pragma unroll
    for (int k = 0; k < 4; ++k) {
        int r = r8 + k * 8;          // r indexes h
        size_t o = (size_t)plane * P_ + (h0 + r) * WW + w0 + col;
        float v = bf16_to_f32(vB[o]) + tile[col][r] + bf16_to_f32(outW[o]);
        vB[o] = f32_to_bf16(v);
    }
}

// ---------- upsample + transpose: high f32 [b][c][64][64] -> highT bf16 [b][p][CCH] ----------
__global__ __launch_bounds__(256) void upsampleT_kernel(const float* __restrict__ high,
                                                        unsigned short* __restrict__ highT) {
    const int h = blockIdx.x, c0 = blockIdx.y * 64, b = blockIdx.z;
    const int tid = threadIdx.x;
    __shared__ float r0[64][65], r1[64][65];
    float fy = 0.5f * h - 0.25f;
    int y0 = (int)floorf(fy);
    float wy = fy - (float)y0;
    int y0c = y0 < 0 ? 0 : y0;
    int y1c = (y0 + 1 > HS - 1) ? (HS - 1) : (y0 + 1);
#pragma unroll
    for (int e = 0; e < 16; ++e) {
        int flat = tid + e * 256;       // 4096 tasks: (c, x)
        int c = flat >> 6, x = flat & 63;
        const float* pl = high + (size_t)(b * CCH + c0 + c) * (HS * WS);
        r0[c][x] = pl[y0c * WS + x];
        r1[c][x] = pl[y1c * WS + x];
    }
    __syncthreads();
#pragma unroll
    for (int e = 0; e < 8; ++e) {
        int flat = tid + e * 256;       // 2048 tasks: (w, c-quad) — 64 ch per block
        int w = flat >> 4, q = flat & 15;
        float fx = 0.5f * w - 0.25f;
        int x0 = (int)floorf(fx);
        float wx = fx - (float)x0;
        int x0c = x0 < 0 ? 0 : x0;
        int x1c = (x0 + 1 > WS - 1) ? (WS - 1) : (x0 + 1);
        u16x4_t o;
#pragma unroll
        for (int k = 0; k < 4; ++k) {
            int c = 4 * q + k;
            float v0 = r0[c][x0c] + wx * (r0[c][x1c] - r0[c][x0c]);
            float v1 = r1[c][x0c] + wx * (r1[c][x1c] - r1[c][x0c]);
            o[k] = f32_to_bf16(v0 + wy * (v1 - v0));
        }
        *(u16x4_t*)&highT[((size_t)(b * P_) + h * WW + w) * CCH + c0 + 4 * q] = o;
    }
}

// ---------- transpose-cast: low f32 [b][CCH][h][w] -> lowT bf16 [b][p][CCH] ----------
__global__ __launch_bounds__(256) void lowT_kernel(const float* __restrict__ low,
                                                   unsigned short* __restrict__ lowT) {
    const int h = blockIdx.x, ch0 = blockIdx.y * 128, b = blockIdx.z;
    const int tid = threadIdx.x;
    __shared__ unsigned short st[128][136];
#pragma unroll
    for (int e = 0; e < 16; ++e) {
        int flat = tid + e * 256;       // 4096 float4 tasks: (c, w-quad)
        int c = flat >> 5, wq = flat & 31;
        float4 u = *(const float4*)(low + (size_t)(b * CCH + ch0 + c) * P_ + h * WW + 4 * wq);
        u16x4_t o;
        o[0] = f32_to_bf16(u.x); o[1] = f32_to_bf16(u.y);
        o[2] = f32_to_bf16(u.z); o[3] = f32_to_bf16(u.w);
        *(u16x4_t*)&st[c][4 * wq] = o;
    }
    __syncthreads();
#pragma unroll
    for (int e = 0; e < 16; ++e) {
        int flat = tid + e * 256;       // 4096 tasks = 128 w x 32 c-quads
        int w = flat >> 5, q = flat & 31;
        u16x4_t o;
#pragma unroll
        for (int k = 0; k < 4; ++k) o[k] = st[4 * q + k][w];
        *(u16x4_t*)&lowT[((size_t)(b * P_) + h * WW + w) * CCH + ch0 + 4 * q] = o;
    }
}

// ---------- transpose: vB bf16 [b][CIN][h][w] -> valT bf16 [b][p][CIN] ----------
__global__ __launch_bounds__(256) void tcast_kernel(const unsigned short* __restrict__ vB,
                                                    unsigned short* __restrict__ valT) {
    const int h = blockIdx.x, b = blockIdx.y;
    const int tid = threadIdx.x;
    __shared__ unsigned short st[CIN][136];
#pragma unroll
    for (int e = 0; e < 8; ++e) {
        int idx = tid + e * 256;        // 2048 bf16x8 tasks: (c, w-oct)
        int c = idx >> 4, oct = idx & 15;
        *(bf16x8_t*)&st[c][oct * 8] =
            *(const bf16x8_t*)&vB[(size_t)(b * CIN + c) * P_ + h * WW + oct * 8];
    }
    __syncthreads();
#pragma unroll
    for (int e = 0; e < 16; ++e) {
        int flat = tid + e * 256;       // 4096 tasks = 128 w x 32 c-quads
        int w = flat >> 5, q = flat & 31;
        u16x4_t o;
#pragma unroll
        for (int k = 0; k < 4; ++k) o[k] = st[4 * q + k][w];
        *(u16x4_t*)&valT[((size_t)(b * P_) + h * WW + w) * CIN + 4 * q] = o;
    }
}

// ---------- fold Wpq = Wq @ Wc1 (16x512) f32 + bf16; bpq = Wq @ bc1 + bq ----------
__global__ __launch_bounds__(256) void fold_wq_kernel(const float* __restrict__ Wq,
                                                      const float* __restrict__ bq,
                                                      const float* __restrict__ Wc1,
                                                      const float* __restrict__ bc1,
                                                      float* __restrict__ Wpq,
                                                      unsigned short* __restrict__ Wpq16,
                                                      float* __restrict__ bpq) {
    int idx = blockIdx.x * 256 + threadIdx.x;
    if (idx < CINT * 2 * CCH) {
        int o = idx / (2 * CCH), i = idx % (2 * CCH);
        float acc = 0.f;
#pragma unroll 8
        for (int m = 0; m < CIN; ++m)
            acc = fmaf(Wq[o * CIN + m], Wc1[m * (2 * CCH) + i], acc);
        Wpq[idx] = acc;
        Wpq16[idx] = f32_to_bf16(acc);
    }
    if (blockIdx.x == 0 && threadIdx.x < CINT) {
        int t = threadIdx.x;
        float acc = bq[t];
        for (int m = 0; m < CIN; ++m) acc = fmaf(Wq[t * CIN + m], bc1[m], acc);
        bpq[t] = acc;
    }
}

// ---------- tiny-M global-direct MFMA conv: D[o<16][p] = sum_k W[o][k]*XT[p][k] + bias ----------
template <int K1, int K2>
__global__ __launch_bounds__(256) void mfma_conv16_kernel(
    const unsigned short* __restrict__ XT1, const unsigned short* __restrict__ XT2,
    const unsigned short* __restrict__ W16, const float* __restrict__ bias,
    float* __restrict__ outF) {
    constexpr int K = K1 + K2;
    const int tid = threadIdx.x, lane = tid & 63, wave = tid >> 6;
    const int p0 = blockIdx.x * 64, b = blockIdx.z;
    const int fl = lane & 15, koff = (lane >> 4) * 8;
    const int pw = p0 + wave * 16 + fl;   // this lane's pixel for B-frags

    const unsigned short* X1b = XT1 + ((size_t)b * P_ + pw) * K1;
    const unsigned short* X2b = (K2 > 0) ? XT2 + ((size_t)b * P_ + pw) * K2
                                         : (const unsigned short*)nullptr;
    f32x4_t acc = (f32x4_t)0.f;
#pragma unroll
    for (int k0 = 0; k0 < K; k0 += 32) {
        bf16x8_t a = *(const bf16x8_t*)&W16[fl * K + k0 + koff];
        bf16x8_t bf;
        if (K2 == 0 || k0 < K1) bf = *(const bf16x8_t*)&X1b[k0 + koff];
        else                    bf = *(const bf16x8_t*)&X2b[(k0 - K1) + koff];
        acc = __builtin_amdgcn_mfma_f32_16x16x32_bf16(a, bf, acc, 0, 0, 0);
    }
#pragma unroll
    for (int j = 0; j < 4; ++j) {
        int o = (lane >> 4) * 4 + j;
        outF[((size_t)(b * CINT + o)) * P_ + p0 + wave * 16 + fl] = acc[j] + bias[o];
    }
}

// ---------- global-direct MFMA conv (128-px tiles): D[c][p] = sum_k W[c][k]*XT[p][k] ----------
// MODE 1: relu(BN) f32 [c][p]. MODE 3: +bias bf16 [c][p]. MODE 4: MODE 3 + bf16 [p][c] (outT).
template <int K1, int K2, int MODE>
__global__ __launch_bounds__(256) void mfma_convT_kernel(
    const unsigned short* __restrict__ XT1, const unsigned short* __restrict__ XT2,
    const unsigned short* __restrict__ W16, const float* __restrict__ bias,
    float* __restrict__ outF, unsigned short* __restrict__ outT,
    unsigned short* __restrict__ outCP, int Cout,
    const float* __restrict__ bn_g, const float* __restrict__ bn_b,
    const float* __restrict__ bn_m, const float* __restrict__ bn_v) {
    constexpr int K = K1 + K2;
    const int tid = threadIdx.x, lane = tid & 63, wave = tid >> 6;
    const int p0 = blockIdx.x * 128, oBase = blockIdx.y * 128, b = blockIdx.z;
    const int fl = lane & 15, koff = (lane >> 4) * 8;

    const unsigned short* X1b = XT1 + ((size_t)b * P_ + p0 + wave * 32) * K1;
    const unsigned short* X2b = (K2 > 0) ? XT2 + ((size_t)b * P_ + p0 + wave * 32) * K2
                                         : (const unsigned short*)nullptr;
    const unsigned short* Wb0 = W16 + (size_t)oBase * K;

    f32x4_t acc[8][2];
#pragma unroll
    for (int ci = 0; ci < 8; ++ci) {
        acc[ci][0] = (f32x4_t)0.f;
        acc[ci][1] = (f32x4_t)0.f;
    }

#pragma unroll 2
    for (int k0 = 0; k0 < K; k0 += 32) {
        bf16x8_t bfr[2];
#pragma unroll
        for (int ni = 0; ni < 2; ++ni) {
            int pr = ni * 16 + fl;
            if (K2 == 0 || k0 < K1)
                bfr[ni] = *(const bf16x8_t*)&X1b[(size_t)pr * K1 + k0 + koff];
            else
                bfr[ni] = *(const bf16x8_t*)&X2b[(size_t)pr * K2 + (k0 - K1) + koff];
        }
        bf16x8_t afr[8];
#pragma unroll
        for (int ci = 0; ci < 8; ++ci)
            afr[ci] = *(const bf16x8_t*)&Wb0[(size_t)(ci * 16 + fl) * K + k0 + koff];
#pragma unroll
        for (int ci = 0; ci < 8; ++ci) {
            acc[ci][0] = __builtin_amdgcn_mfma_f32_16x16x32_bf16(afr[ci], bfr[0], acc[ci][0], 0, 0, 0);
            acc[ci][1] = __builtin_amdgcn_mfma_f32_16x16x32_bf16(afr[ci], bfr[1], acc[ci][1], 0, 0, 0);
        }
    }

    const int csub = (lane >> 4) * 4;
#pragma unroll
    for (int ci = 0; ci < 8; ++ci) {
        int cb = oBase + ci * 16 + csub;
#pragma unroll
        for (int ni = 0; ni < 2; ++ni) {
            int p = p0 + wave * 32 + ni * 16 + fl;
            u16x4_t t;
#pragma unroll
            for (int j = 0; j < 4; ++j) {
                float v = acc[ci][ni][j];
                int o = cb + j;
                if (MODE == 1) {
                    float sc = rsqrtf(bn_v[o] + 1e-5f) * bn_g[o];
                    v = fmaxf((v - bn_m[o]) * sc + bn_b[o], 0.f);
                } else {
                    v += bias ? bias[o] : 0.f;
                }
                if (MODE == 3 || MODE == 4) {
                    unsigned short bv = f32_to_bf16(v);
                    outCP[((size_t)(b * Cout + o)) * P_ + p] = bv;
                    if (MODE == 4) t[j] = bv;
                } else {
                    outF[((size_t)(b * Cout + o)) * P_ + p] = v;
                }
            }
            if (MODE == 4)
                *(u16x4_t*)&outT[((size_t)(b * P_) + p) * Cout + cb] = t;
        }
    }
}

// ---------- fused scores + softmax + attH write + MFMA PV-W -> outW (bf16) ----------
// R22: grid permuted to (H, W/32, B) so the 4 w0-blocks of one (h,b) share an XCD (L2 reuse of pvB).
__global__ __launch_bounds__(256) void attn_fused_w_kernel(
    const float* __restrict__ pq, const float* __restrict__ pk,
    const float* __restrict__ pkT, const unsigned short* __restrict__ pvB,
    const float* __restrict__ gamma_p, unsigned short* __restrict__ outW,
    unsigned short* __restrict__ attH) {
    const int h  = blockIdx.x;              // permuted
    const int w0 = blockIdx.y * 32;         // permuted
    const int b  = blockIdx.z;
    const int tid = threadIdx.x;

    __shared__ float s_s[32][257];
    __shared__ float pq_s[CINT][32];
    __shared__ _Float16 pkW_s[CINT][128];
    __shared__ float rr[32][8];
    __shared__ float rowinv[32];
    __shared__ __align__(16) unsigned short attW_s[32][136];

    for (int e = tid; e < CINT * 32; e += 256) {
        int c = e >> 5, wl = e & 31;
        pq_s[c][wl] = pq[(unsigned)((b * CINT + c) * P_ + h * WW + w0 + wl)];
    }
    for (int e = tid; e < CINT * 128; e += 256) {
        int c = e >> 7, x = e & 127;
        pkW_s[c][x] = (_Float16)pk[(unsigned)((b * CINT + c) * P_ + h * WW + x)];
    }
    __syncthreads();

    const int x = tid;
    if (x < HH) {
        const float* base = pkT + (unsigned)(b * CINT * P_ + w0 * HH + x);
#pragma unroll 2
        for (int wl = 0; wl < 32; ++wl) {
            const float* pp = base + wl * HH;
            float dot = 0.f;
#pragma unroll
            for (int c = 0; c < CINT; ++c)
                dot = fmaf(pq_s[c][wl], pp[c * P_], dot);
            if (x == h) dot = -1e9f;
            s_s[wl][x] = dot;
        }
    } else {
        const int xx = x - HH;
#pragma unroll 4
        for (int wl = 0; wl < 32; ++wl) {
            float dot = 0.f;
#pragma unroll
            for (int c = 0; c < CINT; ++c)
                dot = fmaf(pq_s[c][wl], (float)pkW_s[c][xx], dot);
            s_s[wl][x] = dot;
        }
    }
    __syncthreads();

    const int row = tid >> 3, sub = tid & 7;
    float pm = -3.4e38f;
    for (int xx = sub; xx < 256; xx += 8) pm = fmaxf(pm, s_s[row][xx]);
    rr[row][sub] = pm;
    __syncthreads();
    float m = rr[row][0];
    for (int k = 1; k < 8; ++k) m = fmaxf(m, rr[row][k]);
    float ps = 0.f;
    for (int xx = sub; xx < 256; xx += 8) {
        float ex = __expf(s_s[row][xx] - m);
        s_s[row][xx] = ex;
        ps += ex;
    }
    __syncthreads();
    rr[row][sub] = ps;
    __syncthreads();
    if (sub == 0) {
        float s = 0.f;
        for (int k = 0; k < 8; ++k) s += rr[row][k];
        rowinv[row] = 1.f / s;
    }
    __syncthreads();

#pragma unroll
    for (int e = 0; e < 16; ++e) {
        int idx = tid + e * 256;
        int wl = idx >> 7, xx = idx & 127;
        attH[(((size_t)b * WW + (w0 + wl)) * HH + h) * 128 + xx] =
            f32_to_bf16(s_s[wl][xx] * rowinv[wl]);
    }
#pragma unroll
    for (int e = 0; e < 16; ++e) {
        int idx = tid + e * 256;
        int wl = idx >> 7, xx = idx & 127;
        attW_s[wl][xx] = f32_to_bf16(s_s[wl][128 + xx] * rowinv[wl]);
    }
    __syncthreads();

    // MFMA PV-W: D[c][w] = sum_x pvB[c,h,x] * attW[w,x]  (pvB bf16, direct b128 A-frags)
    const int lane = tid & 63, wave = tid >> 6;
    const int fl = lane & 15, koff = (lane >> 4) * 8;
    const int c0 = wave * 32;
    f32x4_t acc[2][2];
#pragma unroll
    for (int mi = 0; mi < 2; ++mi)
#pragma unroll
        for (int nw = 0; nw < 2; ++nw) acc[mi][nw] = (f32x4_t)0.f;

    const unsigned short* pvBase = pvB + (size_t)b * CIN * P_ + (size_t)h * WW;
#pragma unroll
    for (int ks = 0; ks < 4; ++ks) {
        int x0 = ks * 32 + koff;
        bf16x8_t a0 = *(const bf16x8_t*)&pvBase[(size_t)(c0 + fl) * P_ + x0];
        bf16x8_t a1 = *(const bf16x8_t*)&pvBase[(size_t)(c0 + 16 + fl) * P_ + x0];
        bf16x8_t b0 = *(const bf16x8_t*)&attW_s[fl][x0];
        bf16x8_t b1 = *(const bf16x8_t*)&attW_s[16 + fl][x0];
        acc[0][0] = __builtin_amdgcn_mfma_f32_16x16x32_bf16(a0, b0, acc[0][0], 0, 0, 0);
        acc[0][1] = __builtin_amdgcn_mfma_f32_16x16x32_bf16(a0, b1, acc[0][1], 0, 0, 0);
        acc[1][0] = __builtin_amdgcn_mfma_f32_16x16x32_bf16(a1, b0, acc[1][0], 0, 0, 0);
        acc[1][1] = __builtin_amdgcn_mfma_f32_16x16x32_bf16(a1, b1, acc[1][1], 0, 0, 0);
    }

    const float g = gamma_p[0];
#pragma unroll
    for (int mi = 0; mi < 2; ++mi)
#pragma unroll
        for (int nw = 0; nw < 2; ++nw)
#pragma unroll
            for (int j = 0; j < 4; ++j) {
                int c = c0 + mi * 16 + (lane >> 4) * 4 + j;
                int w = w0 + nw * 16 + fl;
                outW[((size_t)b * CIN + c) * P_ + (size_t)h * WW + w] =
                    f32_to_bf16(g * acc[mi][nw][j]);
            }
}

// ---------- PV-H batched GEMM -> outHT[b][c][w][h] = g * sum_x pvT[c,w,x]*attH[h,x] ----------
// R22: grid permuted to (W, 2, B) so the 2 ch-blocks of one (w,b) share an XCD.
__global__ __launch_bounds__(256) void pv_h_gemm_out_kernel(
    const unsigned short* __restrict__ pvT, const unsigned short* __restrict__ attH,
    const float* __restrict__ gamma_p, unsigned short* __restrict__ outHT) {
    const int w = blockIdx.x, ch = blockIdx.y, b = blockIdx.z;   // permuted
    const int tid = threadIdx.x, lane = tid & 63, wave = tid >> 6;

    __shared__ __align__(16) unsigned short pvs[64][136];
    __shared__ __align__(16) unsigned short ahs[128][136];

    const unsigned short* pvTb = pvT + ((size_t)(b * CIN + ch * 64)) * P_ + (size_t)w * HH;
#pragma unroll
    for (int e = 0; e < 4; ++e) {
        int idx = tid + e * 256;
        int c = idx >> 4, oct = idx & 15;
        *(bf16x8_t*)&pvs[c][oct * 8] = *(const bf16x8_t*)&pvTb[(size_t)c * P_ + oct * 8];
    }
    const unsigned short* ah = attH + ((size_t)b * WW + w) * (HH * 128);
#pragma unroll
    for (int e = 0; e < 8; ++e) {
        int idx = tid + e * 256;
        int hh = idx >> 4, x0 = (idx & 15) * 8;
        *(bf16x8_t*)&ahs[hh][x0] = *(const bf16x8_t*)&ah[(size_t)idx * 8];
    }
    __syncthreads();

    const int fl = lane & 15, koff = (lane >> 4) * 8;
    f32x4_t acc[4][2];
#pragma unroll
    for (int mi = 0; mi < 4; ++mi)
#pragma unroll
        for (int nw = 0; nw < 2; ++nw) acc[mi][nw] = (f32x4_t)0.f;

#pragma unroll
    for (int ks = 0; ks < 4; ++ks) {
        int x0 = ks * 32 + koff;
        bf16x8_t b0 = *(const bf16x8_t*)&ahs[wave * 32 + fl][x0];
        bf16x8_t b1 = *(const bf16x8_t*)&ahs[wave * 32 + 16 + fl][x0];
#pragma unroll
        for (int mi = 0; mi < 4; ++mi) {
            bf16x8_t a = *(const bf16x8_t*)&pvs[mi * 16 + fl][x0];
            acc[mi][0] = __builtin_amdgcn_mfma_f32_16x16x32_bf16(a, b0, acc[mi][0], 0, 0, 0);
            acc[mi][1] = __builtin_amdgcn_mfma_f32_16x16x32_bf16(a, b1, acc[mi][1], 0, 0, 0);
        }
    }

    const float g = gamma_p[0];
    const int csub = (lane >> 4) * 4;
#pragma unroll
    for (int mi = 0; mi < 4; ++mi)
#pragma unroll
        for (int nw = 0; nw < 2; ++nw)
#pragma unroll
            for (int j = 0; j < 4; ++j) {
                int c = ch * 64 + mi * 16 + csub + j;
                int hh = wave * 32 + nw * 16 + fl;
                outHT[((size_t)(b * CIN + c) * WW + w) * HH + hh] =
                    f32_to_bf16(g * acc[mi][nw][j]);
            }
}

extern "C" void kernel_launch(void* const* d_in, const int* in_sizes, int n_in,
                              void* d_out, int out_size, void* d_ws, size_t ws_size,
                              hipStream_t stream) {
    const float* low   = (const float*)d_in[0];
    const float* high  = (const float*)d_in[1];
    const float* Wc1   = (const float*)d_in[2];
    const float* bc1   = (const float*)d_in[3];
    const float* Wc2   = (const float*)d_in[4];
    const float* bc2   = (const float*)d_in[5];
    const float* Wq    = (const float*)d_in[6];
    const float* bq    = (const float*)d_in[7];
    const float* Wk    = (const float*)d_in[8];
    const float* bk    = (const float*)d_in[9];
    const float* Wv    = (const float*)d_in[10];
    const float* bv    = (const float*)d_in[11];
    const float* gamma = (const float*)d_in[12];
    const float* Wb    = (const float*)d_in[13];
    const float* bng   = (const float*)d_in[14];
    const float* bnb   = (const float*)d_in[15];
    const float* bnm   = (const float*)d_in[16];
    const float* bnv   = (const float*)d_in[17];
    float* out = (float*)d_out;   // output is float32

    const unsigned long long outN = (unsigned long long)B_ * CCH * P_;

    // ---- ws layout (f32-eq elems) ----
    const size_t wpqOffA   = 0;
    const size_t bpqOffA   = 8192;
    const size_t wpq16OffA = 8208;
    const size_t wbfOffA   = wpq16OffA + 4096;
    const size_t pqOffA    = wbfOffA + 74784;
    const size_t pkOffA    = pqOffA + (size_t)B_ * CINT * P_;
    const size_t pkTOffA   = pkOffA + (size_t)B_ * CINT * P_;
    const size_t hTOffA    = pkTOffA + (size_t)B_ * CINT * P_;
    const size_t vtAOffA   = hTOffA + ((size_t)B_ * P_ * CCH) / 2;
    const size_t pvTOffA   = vtAOffA + ((size_t)B_ * P_ * CIN) / 2;
    const size_t needA = (pvTOffA + ((size_t)B_ * P_ * CIN) / 2) * sizeof(float);

    if (ws_size < needA) {
        fill_f32_kernel<<<dim3(2048), dim3(256), 0, stream>>>(out, 2.0f, outN);
        return;
    }

    float* Wpq = (float*)d_ws + wpqOffA;
    float* bpq = (float*)d_ws + bpqOffA;
    unsigned short* Wpq16 = (unsigned short*)((float*)d_ws + wpq16OffA);
    unsigned short* Wc2b = (unsigned short*)((float*)d_ws + wbfOffA);
    unsigned short* Wvb  = Wc2b + 32768;
    unsigned short* Wbb  = Wvb + 16384;
    unsigned short* Wkb  = Wbb + 98304;
    float* pqv  = (float*)d_ws + pqOffA;
    float* pkv  = (float*)d_ws + pkOffA;
    float* pkT  = (float*)d_ws + pkTOffA;
    unsigned short* highT = (unsigned short*)((float*)d_ws + hTOffA);
    unsigned short* vtA   = (unsigned short*)((float*)d_ws + vtAOffA);
    unsigned short* pvTb  = (unsigned short*)((float*)d_ws + pvTOffA);

    // d_out scratch: vB bf16 [c][p] (first half). Second half slots:
    //   lowT bf16 (dead after pq conv); per-iter: slot1 = pvB then outHT, slot2 = outW.
    unsigned short* vB = (unsigned short*)out;
    float* half2 = out + (size_t)B_ * CIN * P_;
    unsigned short* lowT  = (unsigned short*)half2;
    unsigned short* slot1 = (unsigned short*)half2;
    unsigned short* slot2 = (unsigned short*)half2 + (size_t)B_ * CIN * P_;

    prep_w_kernel<<<dim3(584), dim3(256), 0, stream>>>(Wc2, Wv, Wb, Wk, Wc2b);
    fold_wq_kernel<<<dim3(32), dim3(256), 0, stream>>>(Wq, bq, Wc1, bc1, Wpq, Wpq16, bpq);
    upsampleT_kernel<<<dim3(HH, CCH / 64, B_), dim3(256), 0, stream>>>(high, highT);
    lowT_kernel<<<dim3(HH, 2, B_), dim3(256), 0, stream>>>(low, lowT);

    // value = Wc2 @ up(high) + bc2  (MODE 4: bf16 vB [c][p] + bf16 vtA [p][c])
    mfma_convT_kernel<256, 0, 4><<<dim3(128, 1, B_), dim3(256), 0, stream>>>(
        highT, (const unsigned short*)0, Wc2b, bc2, (float*)0, vtA, vB, CIN,
        (const float*)0, (const float*)0, (const float*)0, (const float*)0);
    // pq = Wpq @ concat(up(high), low) + bpq  (tiny-M MFMA, K=512)
    mfma_conv16_kernel<256, 256><<<dim3(P_ / 64, 1, B_), dim3(256), 0, stream>>>(
        highT, lowT, Wpq16, bpq, pqv);

    for (int it = 0; it < 2; ++it) {
        // pk = Wk @ value + bk  (tiny-M MFMA, K=128)
        mfma_conv16_kernel<128, 0><<<dim3(P_ / 64, 1, B_), dim3(256), 0, stream>>>(
            vtA, (const unsigned short*)0, Wkb, bk, pkv);
        transpose128_kernel<<<dim3(4, 4, B_ * CINT), dim3(256), 0, stream>>>(pkv, pkT);
        // pv = Wv @ value + bv  (MODE 3: bf16 [c][p] into slot1; lowT dead now)
        mfma_convT_kernel<128, 0, 3><<<dim3(128, 1, B_), dim3(256), 0, stream>>>(
            vtA, (const unsigned short*)0, Wvb, bv, (float*)0, (unsigned short*)0, slot1, CIN,
            (const float*)0, (const float*)0, (const float*)0, (const float*)0);
        transpose128_b16_kernel<<<dim3(4, 4, B_ * CIN), dim3(256), 0, stream>>>(slot1, pvTb);
        // attn: grid (H, W/32, B) — XCD-friendly; outW -> slot2, attH -> vtA
        attn_fused_w_kernel<<<dim3(HH, WW / 32, B_), dim3(256), 0, stream>>>(
            pqv, pkv, pkT, slot1, gamma, slot2, vtA);
        // H-direction PV -> outHT (slot1); grid (W, 2, B) — XCD-friendly
        pv_h_gemm_out_kernel<<<dim3(WW, 2, B_), dim3(256), 0, stream>>>(
            pvTb, vtA, gamma, slot1);
        // vB += outW + outHT^T  (single fused bf16 RMW pass)
        merge_hw_kernel<<<dim3(4, 4, B_ * CIN), dim3(256), 0, stream>>>(slot1, slot2, vB);
        // refresh valueT (overwrites attH in vtA)
        tcast_kernel<<<dim3(HH, B_), dim3(256), 0, stream>>>(vB, vtA);
    }
    // out = relu(BN(Wb @ concat(value, up(high))))  (MODE 1, 128-px tiles) — overwrites d_out
    mfma_convT_kernel<128, 256, 1><<<dim3(128, 2, B_), dim3(256), 0, stream>>>(
        vtA, highT, Wbb, (const float*)0, out, (unsigned short*)0, (unsigned short*)0, CCH,
        bng, bnb, bnm, bnv);
}